// Round 6
// baseline (110.037 us; speedup 1.0000x reference)
//
#include <hip/hip_runtime.h>
#include <math.h>

// Levinson-Durbin, 8 lanes per batch, all state in NAMED SCALARS (no arrays,
// no vectors, no lambdas — nothing SROA can fail to promote).
//
// lane s (0..7) of an 8-lane group holds, for j = 0..7:
//   rr_j = r[8s+1+j], aa_j = A[8s+1+j], bb_j = Bb[8s+j]
// Per iteration m = 1..64:
//   acc = sum bb*rr   (8 lane-local FMA + 3-step xor butterfly over 8 lanes)
//   k   = -acc * rcp(E)                      (v_rcp_f32, ~1e-7 rel err)
//   descending zero-copy update:
//     aa_i = fma(k, bb_i, aa_i); bb_i = fma(k, aa_{i-1}, bb_{i-1})
//     (descending order => every RHS operand is pre-overwrite; no temps)
//   bb_0 = k on s==0 else fma(k, paa, pbb) with prev-lane trailing elems
//   E    = fma(-k*k, E, E)
// Output: a[i] = aa, K = sqrt(E).

constexpr int M    = 64;
constexpr int EL   = M + 1;        // 65 floats per row
constexpr int LPB  = 8;            // lanes per batch
constexpr int BT   = 256;          // threads per block
constexpr int ROWS = BT / LPB;     // 32 batches per block

__global__ __launch_bounds__(BT, 8) void levinson_kernel(const float* __restrict__ rin,
                                                         float* __restrict__ out) {
  __shared__ float smem[ROWS * EL];   // 8,320 B
  const int tid = threadIdx.x;
  const size_t base = (size_t)blockIdx.x * (ROWS * EL);

  // ---- coalesced stage-in: global float4 -> LDS (8320 B % 16 == 0) ----
  {
    const int n4 = (ROWS * EL) >> 2;  // 520, exact
    const float4* in4 = reinterpret_cast<const float4*>(rin + base);
    float4* s4 = reinterpret_cast<float4*>(smem);
    for (int i = tid; i < n4; i += BT) s4[i] = in4[i];
  }
  __syncthreads();

  const int row = tid >> 3;           // local batch (0..31)
  const int s   = tid & 7;            // sub-lane within batch
  const float* rrow = &smem[row * EL];
  const int rbase = 8 * s + 1;

  // 24 named state floats — guaranteed register-resident
  const float rr0 = rrow[rbase + 0], rr1 = rrow[rbase + 1];
  const float rr2 = rrow[rbase + 2], rr3 = rrow[rbase + 3];
  const float rr4 = rrow[rbase + 4], rr5 = rrow[rbase + 5];
  const float rr6 = rrow[rbase + 6], rr7 = rrow[rbase + 7];
  float aa0 = 0.f, aa1 = 0.f, aa2 = 0.f, aa3 = 0.f;
  float aa4 = 0.f, aa5 = 0.f, aa6 = 0.f, aa7 = 0.f;
  float bb0 = (s == 0) ? 1.f : 0.f;   // b_0 = delta_0
  float bb1 = 0.f, bb2 = 0.f, bb3 = 0.f;
  float bb4 = 0.f, bb5 = 0.f, bb6 = 0.f, bb7 = 0.f;
  float E = rrow[0];

#pragma unroll 1
  for (int m = 0; m < M; ++m) {
    // prev-lane trailing elements (old values) — issue DS early, overlap dot
    const float pbb = __shfl_up(bb7, 1);
    const float paa = __shfl_up(aa7, 1);

    // partial dot: 4 independent 2-deep chains
    float p0 = bb0 * rr0, p1 = bb1 * rr1, p2 = bb2 * rr2, p3 = bb3 * rr3;
    p0 = fmaf(bb4, rr4, p0); p1 = fmaf(bb5, rr5, p1);
    p2 = fmaf(bb6, rr6, p2); p3 = fmaf(bb7, rr7, p3);
    float acc = (p0 + p1) + (p2 + p3);
    acc += __shfl_xor(acc, 1);        // butterfly across the 8-lane group
    acc += __shfl_xor(acc, 2);
    acc += __shfl_xor(acc, 4);

    const float k = -acc * __builtin_amdgcn_rcpf(E);

    // descending zero-copy update: every RHS read happens pre-overwrite
    aa7 = fmaf(k, bb7, aa7); bb7 = fmaf(k, aa6, bb6);
    aa6 = fmaf(k, bb6, aa6); bb6 = fmaf(k, aa5, bb5);
    aa5 = fmaf(k, bb5, aa5); bb5 = fmaf(k, aa4, bb4);
    aa4 = fmaf(k, bb4, aa4); bb4 = fmaf(k, aa3, bb3);
    aa3 = fmaf(k, bb3, aa3); bb3 = fmaf(k, aa2, bb2);
    aa2 = fmaf(k, bb2, aa2); bb2 = fmaf(k, aa1, bb1);
    aa1 = fmaf(k, bb1, aa1); bb1 = fmaf(k, aa0, bb0);
    aa0 = fmaf(k, bb0, aa0);
    bb0 = (s == 0) ? k : fmaf(k, paa, pbb);

    E = fmaf(-k * k, E, E);           // E *= (1 - k^2)
  }

  __syncthreads();                    // input consumed; reuse smem for output

  {
    float* orow = &smem[row * EL];
    if (s == 0) orow[0] = sqrtf(E);
    orow[rbase + 0] = aa0; orow[rbase + 1] = aa1;
    orow[rbase + 2] = aa2; orow[rbase + 3] = aa3;
    orow[rbase + 4] = aa4; orow[rbase + 5] = aa5;
    orow[rbase + 6] = aa6; orow[rbase + 7] = aa7;
  }
  __syncthreads();

  // ---- coalesced stage-out: LDS -> global float4 ----
  {
    const int n4 = (ROWS * EL) >> 2;
    const float4* s4 = reinterpret_cast<const float4*>(smem);
    float4* out4 = reinterpret_cast<float4*>(out + base);
    for (int i = tid; i < n4; i += BT) out4[i] = s4[i];
  }
}

extern "C" void kernel_launch(void* const* d_in, const int* in_sizes, int n_in,
                              void* d_out, int out_size, void* d_ws, size_t ws_size,
                              hipStream_t stream) {
  const float* r = (const float*)d_in[0];
  float* out = (float*)d_out;
  const int B = in_sizes[0] / EL;            // 65536
  const int blocks = B / ROWS;               // 2048, exact
  levinson_kernel<<<blocks, BT, 0, stream>>>(r, out);
}